// Round 2
// baseline (496.667 us; speedup 1.0000x reference)
//
#include <hip/hip_runtime.h>
#include <hip/hip_bf16.h>

typedef __hip_bfloat16 bf16;
#define CC 64
#define KK 16
#define EPSV 1e-5f

struct Params {
  const float* points; const float* features; const int* gidx;
  const float *Wq,*bq,*Wk,*bk,*Wv,*bv,*Wp,*b_p;
  const float *bnp_g,*bnp_b,*bnp_m,*bnp_v;
  const float *Wg1,*bg1,*bng_g,*bng_b,*bng_m,*bng_v;
  const float *Wg2,*bg2,*Wo,*bo;
  bf16* q; bf16* k; bf16* v;
  float* WpF; float* bpF; float* W1F; float* b1F;
  float* W2F; float* b2F; float* WoF; float* boF;
  float* out; int N;
};

__device__ __forceinline__ float b2f(bf16 x){ return __bfloat162float(x); }

// Fold eval-mode BN into weights/biases.
// bn(x) = (x-m)*g*rsqrt(v+eps)+b = x*S + (b - m*S), S = g*rsqrt(v+eps)
__global__ void prep_kernel(Params P){
  int t = threadIdx.x;
  for (int idx = t; idx < 192; idx += blockDim.x){
    int ch = idx & 63;
    float S = P.bnp_g[ch] * rsqrtf(P.bnp_v[ch] + EPSV);
    P.WpF[idx] = P.Wp[idx] * S;
  }
  for (int ch = t; ch < 64; ch += blockDim.x){
    float S = P.bnp_g[ch] * rsqrtf(P.bnp_v[ch] + EPSV);
    float O = P.bnp_b[ch] - P.bnp_m[ch] * S;
    P.bpF[ch] = P.b_p[ch] * S + O;
    float Sg = P.bng_g[ch] * rsqrtf(P.bng_v[ch] + EPSV);
    float Og = P.bng_b[ch] - P.bng_m[ch] * Sg;
    P.b1F[ch] = P.bg1[ch] * Sg + Og;
    P.b2F[ch] = P.bg2[ch];
    P.boF[ch] = P.bo[ch];
  }
  for (int idx = t; idx < 4096; idx += blockDim.x){
    int ch = idx & 63;
    float Sg = P.bng_g[ch] * rsqrtf(P.bng_v[ch] + EPSV);
    P.W1F[idx] = P.Wg1[idx] * Sg;
    P.W2F[idx] = P.Wg2[idx];
    P.WoF[idx] = P.Wo[idx];
  }
}

// q,k,v = features @ W + b.  16 points per block; 4 waves; each wave computes
// all 64 channels for 4 points, loading each weight element once.
#define QP 16
__global__ void __launch_bounds__(256) qkv_kernel(Params P){
  __shared__ float sF[QP][CC];
  int base = blockIdx.x * QP;
  int t = threadIdx.x;
  int c = t & 63;
  int wg = t >> 6;            // wave id 0..3 -> points base+wg*4 .. +3
  // stage features (16x64 fp32) cooperatively, coalesced
  for (int idx = t; idx < QP*CC; idx += 256){
    int p = idx >> 6;
    sF[p][idx & 63] = (base + p < P.N) ? P.features[(size_t)(base+p)*CC + (idx&63)] : 0.f;
  }
  __syncthreads();
  float qa0=P.bq[c], qa1=qa0, qa2=qa0, qa3=qa0;
  float ka0=P.bk[c], ka1=ka0, ka2=ka0, ka3=ka0;
  float va0=P.bv[c], va1=va0, va2=va0, va3=va0;
  const float* f0 = sF[wg*4+0]; const float* f1 = sF[wg*4+1];
  const float* f2 = sF[wg*4+2]; const float* f3 = sF[wg*4+3];
  #pragma unroll 8
  for (int e = 0; e < CC; e++){
    float wq = P.Wq[e*CC+c], wk = P.Wk[e*CC+c], wv = P.Wv[e*CC+c];
    float a0 = f0[e], a1 = f1[e], a2 = f2[e], a3 = f3[e];
    qa0 = fmaf(a0, wq, qa0); qa1 = fmaf(a1, wq, qa1);
    qa2 = fmaf(a2, wq, qa2); qa3 = fmaf(a3, wq, qa3);
    ka0 = fmaf(a0, wk, ka0); ka1 = fmaf(a1, wk, ka1);
    ka2 = fmaf(a2, wk, ka2); ka3 = fmaf(a3, wk, ka3);
    va0 = fmaf(a0, wv, va0); va1 = fmaf(a1, wv, va1);
    va2 = fmaf(a2, wv, va2); va3 = fmaf(a3, wv, va3);
  }
  int p0 = base + wg*4;
  if (p0+0 < P.N){ P.q[(size_t)(p0+0)*CC+c]=__float2bfloat16(qa0); P.k[(size_t)(p0+0)*CC+c]=__float2bfloat16(ka0); P.v[(size_t)(p0+0)*CC+c]=__float2bfloat16(va0); }
  if (p0+1 < P.N){ P.q[(size_t)(p0+1)*CC+c]=__float2bfloat16(qa1); P.k[(size_t)(p0+1)*CC+c]=__float2bfloat16(ka1); P.v[(size_t)(p0+1)*CC+c]=__float2bfloat16(va1); }
  if (p0+2 < P.N){ P.q[(size_t)(p0+2)*CC+c]=__float2bfloat16(qa2); P.k[(size_t)(p0+2)*CC+c]=__float2bfloat16(ka2); P.v[(size_t)(p0+2)*CC+c]=__float2bfloat16(va2); }
  if (p0+3 < P.N){ P.q[(size_t)(p0+3)*CC+c]=__float2bfloat16(qa3); P.k[(size_t)(p0+3)*CC+c]=__float2bfloat16(ka3); P.v[(size_t)(p0+3)*CC+c]=__float2bfloat16(va3); }
}

// Main per-point kernel: one wave per point, thread c = channel c.
// Wg1/Wg2 columns (BN-folded) live in registers (128 VGPRs).
__global__ void __launch_bounds__(64,2) main_kernel(Params P){
  __shared__ __align__(16) float sP[KK*CC];
  __shared__ __align__(16) float sA[KK*CC];
  __shared__ __align__(16) float sT[CC];
  __shared__ int sI[KK];
  const int i = blockIdx.x; const int c = threadIdx.x;

  float w1[CC], w2[CC];
  #pragma unroll
  for (int e = 0; e < CC; e++){ w1[e] = P.W1F[e*CC+c]; }
  #pragma unroll
  for (int e = 0; e < CC; e++){ w2[e] = P.W2F[e*CC+c]; }

  if (c < KK) sI[c] = P.gidx[(size_t)i*KK + c];
  float qc = b2f(P.q[(size_t)i*CC + c]);
  float px = P.points[(size_t)i*3+0];
  float py = P.points[(size_t)i*3+1];
  float pz = P.points[(size_t)i*3+2];
  float wp0 = P.WpF[c], wp1 = P.WpF[CC+c], wp2 = P.WpF[2*CC+c], bp = P.bpF[c];
  float b1 = P.b1F[c], bb2 = P.b2F[c];
  __syncthreads();

  // Phase 1: gathers + p (BN+relu folded) + a = q - k + p
  #pragma unroll 4
  for (int j = 0; j < KK; j++){
    int idx = sI[j];
    float rx = P.points[(size_t)idx*3+0] - px;
    float ry = P.points[(size_t)idx*3+1] - py;
    float rz = P.points[(size_t)idx*3+2] - pz;
    float pv = fmaxf(fmaf(rx, wp0, fmaf(ry, wp1, fmaf(rz, wp2, bp))), 0.f);
    sP[j*CC+c] = pv;
    float kv = b2f(P.k[(size_t)idx*CC + c]);
    sA[j*CC+c] = qc - kv + pv;
  }
  __syncthreads();

  // Phase 2: h[j] = relu(a@W1+b1) @ W2 + b2 per neighbor; h stays in regs
  float h[KK];
  const float4* sA4 = (const float4*)sA;
  const float4* sT4 = (const float4*)sT;
  #pragma unroll
  for (int j = 0; j < KK; j++){
    float t0 = b1, t1 = 0.f, t2 = 0.f, t3 = 0.f;
    #pragma unroll
    for (int e4 = 0; e4 < 16; e4++){
      float4 a4 = sA4[j*16 + e4];
      t0 = fmaf(a4.x, w1[e4*4+0], t0);
      t1 = fmaf(a4.y, w1[e4*4+1], t1);
      t2 = fmaf(a4.z, w1[e4*4+2], t2);
      t3 = fmaf(a4.w, w1[e4*4+3], t3);
    }
    float tv = fmaxf((t0+t1)+(t2+t3), 0.f);
    __syncthreads();           // prev iteration's sT reads done
    sT[c] = tv;
    __syncthreads();
    float h0 = bb2, h1 = 0.f, h2 = 0.f, h3 = 0.f;
    #pragma unroll
    for (int e4 = 0; e4 < 16; e4++){
      float4 t4 = sT4[e4];
      h0 = fmaf(t4.x, w2[e4*4+0], h0);
      h1 = fmaf(t4.y, w2[e4*4+1], h1);
      h2 = fmaf(t4.z, w2[e4*4+2], h2);
      h3 = fmaf(t4.w, w2[e4*4+3], h3);
    }
    h[j] = (h0+h1)+(h2+h3);
  }

  // Phase 3: softmax over neighbors (per-channel, all in registers)
  float m = h[0];
  #pragma unroll
  for (int j = 1; j < KK; j++) m = fmaxf(m, h[j]);
  float s = 0.f;
  #pragma unroll
  for (int j = 0; j < KK; j++){ h[j] = __expf(h[j]-m); s += h[j]; }
  float inv = 1.f / s;

  // Phase 4: pre[c] = sum_j (v_gathered + p) * attn
  float pre = 0.f;
  #pragma unroll
  for (int j = 0; j < KK; j++){
    int idx = sI[j];
    float gv = b2f(P.v[(size_t)idx*CC + c]);
    pre = fmaf(gv + sP[j*CC+c], h[j], pre);
  }
  pre *= inv;

  // Phase 5: out = pre @ Wo + bo
  __syncthreads();
  sT[c] = pre;
  __syncthreads();
  float o0 = P.boF[c], o1 = 0.f, o2 = 0.f, o3 = 0.f;
  #pragma unroll
  for (int e4 = 0; e4 < 16; e4++){
    float4 t4 = sT4[e4];
    o0 = fmaf(t4.x, P.WoF[(e4*4+0)*CC+c], o0);
    o1 = fmaf(t4.y, P.WoF[(e4*4+1)*CC+c], o1);
    o2 = fmaf(t4.z, P.WoF[(e4*4+2)*CC+c], o2);
    o3 = fmaf(t4.w, P.WoF[(e4*4+3)*CC+c], o3);
  }
  P.out[(size_t)i*CC + c] = (o0+o1)+(o2+o3);
}

extern "C" void kernel_launch(void* const* d_in, const int* in_sizes, int n_in,
                              void* d_out, int out_size, void* d_ws, size_t ws_size,
                              hipStream_t stream){
  Params P;
  P.points   = (const float*)d_in[0];
  P.features = (const float*)d_in[1];
  P.gidx     = (const int*)d_in[2];
  P.Wq  = (const float*)d_in[3];  P.bq  = (const float*)d_in[4];
  P.Wk  = (const float*)d_in[5];  P.bk  = (const float*)d_in[6];
  P.Wv  = (const float*)d_in[7];  P.bv  = (const float*)d_in[8];
  P.Wp  = (const float*)d_in[9];  P.b_p = (const float*)d_in[10];
  P.bnp_g = (const float*)d_in[11]; P.bnp_b = (const float*)d_in[12];
  P.bnp_m = (const float*)d_in[13]; P.bnp_v = (const float*)d_in[14];
  P.Wg1 = (const float*)d_in[15]; P.bg1 = (const float*)d_in[16];
  P.bng_g = (const float*)d_in[17]; P.bng_b = (const float*)d_in[18];
  P.bng_m = (const float*)d_in[19]; P.bng_v = (const float*)d_in[20];
  P.Wg2 = (const float*)d_in[21]; P.bg2 = (const float*)d_in[22];
  P.Wo  = (const float*)d_in[23]; P.bo  = (const float*)d_in[24];
  const int N = in_sizes[0] / 3;
  P.N = N;

  bf16* wsb = (bf16*)d_ws;
  P.q = wsb;                        // N*64 bf16
  P.k = P.q + (size_t)N*CC;         // N*64 bf16
  P.v = P.k + (size_t)N*CC;         // N*64 bf16
  float* wb = (float*)(P.v + (size_t)N*CC);
  P.WpF = wb; wb += 192;
  P.bpF = wb; wb += 64;
  P.W1F = wb; wb += 4096;
  P.b1F = wb; wb += 64;
  P.W2F = wb; wb += 4096;
  P.b2F = wb; wb += 64;
  P.WoF = wb; wb += 4096;
  P.boF = wb; wb += 64;
  P.out = (float*)d_out;

  hipLaunchKernelGGL(prep_kernel, dim3(1), dim3(256), 0, stream, P);
  hipLaunchKernelGGL(qkv_kernel,  dim3((N + QP - 1)/QP), dim3(256), 0, stream, P);
  hipLaunchKernelGGL(main_kernel, dim3(N), dim3(64), 0, stream, P);
}

// Round 3
// 258.159 us; speedup vs baseline: 1.9239x; 1.9239x over previous
//
#include <hip/hip_runtime.h>
#include <hip/hip_bf16.h>

#define EPSV 1e-5f
#define TW 4   // waves per block

typedef __attribute__((ext_vector_type(8))) short s8v;
typedef __attribute__((ext_vector_type(4))) float f4v;

struct InP {
  const float *points, *features; const int* gidx;
  const float *Wq,*bq,*Wk,*bk,*Wv,*bv,*Wp,*b_p;
  const float *bnp_g,*bnp_b,*bnp_m,*bnp_v;
  const float *Wg1,*bg1,*bng_g,*bng_b,*bng_m,*bng_v;
  const float *Wg2,*bg2,*Wo,*bo;
  float* out; int N;
};
struct WS {
  unsigned short *qW1, *kT, *vT;                     // N x 64 bf16 each
  unsigned short *WAf, *Wkf, *Wvf, *W1f, *W2f, *Wof; // 8 frags x 64 lanes x 8 bf16
  unsigned short *Wpf;                               // 4 frags x 64 x 8
  float *bq1F, *bpF;                                 // 64 fp32 each
};

__device__ __forceinline__ unsigned short f2bf(float x){
  __hip_bfloat16 h = __float2bfloat16(x);
  unsigned short u; __builtin_memcpy(&u, &h, 2); return u;
}
__device__ __forceinline__ float bf2f(unsigned short s){
  union{unsigned u; float f;} c; c.u = ((unsigned)s) << 16; return c.f;
}
__device__ __forceinline__ unsigned pk2(float x, float y){
  __hip_bfloat162 h = __float22bfloat162_rn(make_float2(x, y));
  unsigned u; __builtin_memcpy(&u, &h, 4); return u;
}
__device__ __forceinline__ s8v pack8(f4v x0, f4v x1){
  s8v r;
  ((unsigned*)&r)[0] = pk2(x0[0], x0[1]);
  ((unsigned*)&r)[1] = pk2(x0[2], x0[3]);
  ((unsigned*)&r)[2] = pk2(x1[0], x1[1]);
  ((unsigned*)&r)[3] = pk2(x1[2], x1[3]);
  return r;
}
__device__ __forceinline__ s8v pack8sub(f4v x0, f4v x1, s8v k){
  s8v r;
  ((unsigned*)&r)[0] = pk2(x0[0]-bf2f((unsigned short)k[0]), x0[1]-bf2f((unsigned short)k[1]));
  ((unsigned*)&r)[1] = pk2(x0[2]-bf2f((unsigned short)k[2]), x0[3]-bf2f((unsigned short)k[3]));
  ((unsigned*)&r)[2] = pk2(x1[0]-bf2f((unsigned short)k[4]), x1[1]-bf2f((unsigned short)k[5]));
  ((unsigned*)&r)[3] = pk2(x1[2]-bf2f((unsigned short)k[6]), x1[3]-bf2f((unsigned short)k[7]));
  return r;
}

// ---------------- prep: BN folds + B-fragment swizzles -------------------
// B-frag layout (16x16x32): B[k][n], n = nt*16 + (lane&15), k = ks*32 + (lane>>4)*8 + j.
// Stored flat: frag f = nt*2+ks; elem at ((f*64 + lane)*8 + j).
__global__ void prep_kernel(InP P, WS W){
  const int t = threadIdx.x;
  __shared__ float Sg[64], SpS[64];
  if (t < 64){
    Sg[t]  = P.bng_g[t] * rsqrtf(P.bng_v[t] + EPSV);
    SpS[t] = P.bnp_g[t] * rsqrtf(P.bnp_v[t] + EPSV);
  }
  __syncthreads();
  for (int e = t; e < 512; e += 256){
    int f = e >> 6, L = e & 63;
    int ks = f & 1, nt = f >> 1;
    int n = nt*16 + (L & 15);
    int kb = ks*32 + ((L >> 4) << 3);
    float sg = Sg[n];
    for (int j = 0; j < 8; j++){
      int k = kb + j;
      W.W1f[e*8+j] = f2bf(P.Wg1[k*64+n] * sg);
      W.W2f[e*8+j] = f2bf(P.Wg2[k*64+n]);
      W.Wof[e*8+j] = f2bf(P.Wo [k*64+n]);
      W.Wkf[e*8+j] = f2bf(P.Wk [k*64+n]);
      W.Wvf[e*8+j] = f2bf(P.Wv [k*64+n]);
      float acc = 0.f;
      for (int d = 0; d < 64; d++) acc += P.Wq[k*64+d] * P.Wg1[d*64+n];
      W.WAf[e*8+j] = f2bf(acc * sg);
    }
  }
  // Wp frags: K=32 MFMA, only k<3 nonzero
  for (int e = t; e < 256; e += 256){
    int nt = e >> 6, L = e & 63;
    int n = nt*16 + (L & 15);
    int kb = (L >> 4) << 3;
    for (int j = 0; j < 8; j++){
      int k = kb + j;
      float v = (k < 3) ? P.Wp[k*64+n] * SpS[n] : 0.f;
      W.Wpf[e*8+j] = f2bf(v);
    }
  }
  if (t < 64){
    float acc = 0.f;
    for (int d = 0; d < 64; d++) acc += P.bq[d] * P.Wg1[d*64+t];
    // bq1F = bq@W1F + b1F  (b1F includes BN fold of bg1)
    W.bq1F[t] = acc*Sg[t] + P.bg1[t]*Sg[t] + P.bng_b[t] - P.bng_m[t]*Sg[t];
    W.bpF[t]  = P.b_p[t]*SpS[t] + P.bnp_b[t] - P.bnp_m[t]*SpS[t];
  }
}

// ---------------- qkv: qW1 = f@(Wq@W1F)+bq1F ; k = f@Wk+bk ; v = f@Wv+bv --
__global__ void __launch_bounds__(256) qkv_kernel(InP P, WS W){
  const int tid = threadIdx.x;
  const int wid = tid >> 6, l = tid & 63;
  const int cl = l & 15, q = l >> 4;
  const int TILES = (P.N + 15) >> 4;
  const int task = blockIdx.x * TW + wid;
  if (task >= TILES) return;
  const int i0 = task * 16;
  int row = i0 + cl; if (row > P.N - 1) row = P.N - 1;
  // A-frags from features (fp32 -> bf16)
  const float* fr = P.features + (size_t)row*64 + q*8;
  f4v x0 = *(const f4v*)fr;
  f4v x1 = *(const f4v*)(fr + 4);
  s8v fa0 = pack8(x0, x1);
  x0 = *(const f4v*)(fr + 32);
  x1 = *(const f4v*)(fr + 36);
  s8v fa1 = pack8(x0, x1);

  auto doMat = [&](const unsigned short* Bf_, const float* biasPtr, unsigned short* outPtr){
    const s8v* Bf = (const s8v*)Bf_;
    #pragma unroll
    for (int nt = 0; nt < 4; nt++){
      float bn = biasPtr[nt*16 + cl];
      f4v ci = { bn, bn, bn, bn };
      f4v c = __builtin_amdgcn_mfma_f32_16x16x32_bf16(fa0, Bf[(2*nt+0)*64 + l], ci, 0, 0, 0);
      c = __builtin_amdgcn_mfma_f32_16x16x32_bf16(fa1, Bf[(2*nt+1)*64 + l], c, 0, 0, 0);
      #pragma unroll
      for (int r = 0; r < 4; r++){
        int rg = i0 + q*4 + r;
        if (rg < P.N) outPtr[(size_t)rg*64 + nt*16 + cl] = f2bf(c[r]);
      }
    }
  };
  doMat(W.WAf, W.bq1F, W.qW1);
  doMat(W.Wkf, P.bk,   W.kT);
  doMat(W.Wvf, P.bv,   W.vT);
}

// ---------------- main: per-wave point loop, all GEMMs on MFMA -----------
// Per wave LDS slices (no __syncthreads needed anywhere):
//   Sp  [16][68] fp32 : p / T transpose scratch (C-layout write, A-layout read)
//   Vg  [16][136] bf16: gathered v rows (A-layout write, C-layout scalar read)
//   PreB[16][68] fp32 : per-point pre-activation rows for the inline Wo epilogue
__global__ void __launch_bounds__(256, 2) main_kernel(InP P, WS W){
  __shared__ __align__(16) float Sp[TW][16*68];
  __shared__ __align__(16) float PreB[TW][16*68];
  __shared__ __align__(16) unsigned short Vg[TW][16*136];
  const int tid = threadIdx.x;
  const int wid = tid >> 6, l = tid & 63;
  const int cl = l & 15, q = l >> 4;
  const int TILES = (P.N + 15) >> 4;
  const int task = blockIdx.x * TW + wid;
  if (task >= TILES) return;
  const int i0 = task * 16;
  float* Spw = Sp[wid];
  float* PreBw = PreB[wid];
  unsigned short* Vgw = Vg[wid];

  // held B-frags: W1 (BN-folded), W2, Wp
  s8v w1f[8], w2f[8], wpf[4];
  {
    const s8v* W1p = (const s8v*)W.W1f;
    const s8v* W2p = (const s8v*)W.W2f;
    const s8v* Wpp = (const s8v*)W.Wpf;
    #pragma unroll
    for (int f = 0; f < 8; f++){ w1f[f] = W1p[f*64 + l]; w2f[f] = W2p[f*64 + l]; }
    #pragma unroll
    for (int f = 0; f < 4; f++) wpf[f] = Wpp[f*64 + l];
  }
  float bp4[4], b24[4];
  #pragma unroll
  for (int nt = 0; nt < 4; nt++){ bp4[nt] = W.bpF[nt*16 + cl]; b24[nt] = P.bg2[nt*16 + cl]; }

  #pragma unroll 1
  for (int pt = 0; pt < 16; pt++){
    const int i = i0 + pt;
    if (i < P.N){
      const int idx = P.gidx[(size_t)i*16 + cl];
      // k gather in A-layout (bf16x8 per k-half)
      const s8v* kr = (const s8v*)(W.kT + (size_t)idx*64);
      s8v gk0 = kr[q], gk1 = kr[4 + q];
      // geometry -> p A-frag (K=3 padded to 32)
      const float pix = P.points[(size_t)i*3+0];
      const float piy = P.points[(size_t)i*3+1];
      const float piz = P.points[(size_t)i*3+2];
      float rx = 0.f, ry = 0.f, rz = 0.f;
      if (l < 16){
        const float* gp = P.points + (size_t)idx*3;
        rx = gp[0]-pix; ry = gp[1]-piy; rz = gp[2]-piz;
      }
      s8v ap;
      ((unsigned*)&ap)[0] = pk2(rx, ry);
      ((unsigned*)&ap)[1] = pk2(rz, 0.f);
      ((unsigned*)&ap)[2] = 0u;
      ((unsigned*)&ap)[3] = 0u;
      // p = relu(rel @ WpF + bpF)  (C-layout tiles)
      f4v pc[4];
      #pragma unroll
      for (int nt = 0; nt < 4; nt++){
        f4v ci = { bp4[nt], bp4[nt], bp4[nt], bp4[nt] };
        pc[nt] = __builtin_amdgcn_mfma_f32_16x16x32_bf16(ap, wpf[nt], ci, 0, 0, 0);
      }
      #pragma unroll
      for (int nt = 0; nt < 4; nt++)
        #pragma unroll
        for (int r = 0; r < 4; r++) pc[nt][r] = fmaxf(pc[nt][r], 0.f);
      // p -> LDS (C-layout write)
      #pragma unroll
      for (int nt = 0; nt < 4; nt++)
        #pragma unroll
        for (int r = 0; r < 4; r++)
          Spw[(q*4+r)*68 + nt*16 + cl] = pc[nt][r];
      // GEMM1 C-init = qW1 row (q@W1F + b1F folded)
      float qc4[4];
      #pragma unroll
      for (int nt = 0; nt < 4; nt++) qc4[nt] = bf2f(W.qW1[(size_t)i*64 + nt*16 + cl]);
      // read p in A-layout, a' = p - gk
      s8v af0, af1;
      {
        const f4v* pr = (const f4v*)&Spw[cl*68 + q*8];
        af0 = pack8sub(pr[0], pr[1], gk0);
        pr = (const f4v*)&Spw[cl*68 + 32 + q*8];
        af1 = pack8sub(pr[0], pr[1], gk1);
      }
      // T = relu(a' @ W1F + qW1)
      f4v tc[4];
      #pragma unroll
      for (int nt = 0; nt < 4; nt++){
        f4v ci = { qc4[nt], qc4[nt], qc4[nt], qc4[nt] };
        tc[nt] = __builtin_amdgcn_mfma_f32_16x16x32_bf16(af0, w1f[2*nt+0], ci, 0, 0, 0);
        tc[nt] = __builtin_amdgcn_mfma_f32_16x16x32_bf16(af1, w1f[2*nt+1], tc[nt], 0, 0, 0);
        #pragma unroll
        for (int r = 0; r < 4; r++) tc[nt][r] = fmaxf(tc[nt][r], 0.f);
      }
      // T -> LDS (C-layout), read back in A-layout as bf16
      #pragma unroll
      for (int nt = 0; nt < 4; nt++)
        #pragma unroll
        for (int r = 0; r < 4; r++)
          Spw[(q*4+r)*68 + nt*16 + cl] = tc[nt][r];
      s8v tf0, tf1;
      {
        const f4v* pr = (const f4v*)&Spw[cl*68 + q*8];
        tf0 = pack8(pr[0], pr[1]);
        pr = (const f4v*)&Spw[cl*68 + 32 + q*8];
        tf1 = pack8(pr[0], pr[1]);
      }
      // v gather -> Vg (A-layout rows, raw bf16)
      const s8v* vr = (const s8v*)(W.vT + (size_t)idx*64);
      *(s8v*)&Vgw[cl*136 + q*8]      = vr[q];
      *(s8v*)&Vgw[cl*136 + 32 + q*8] = vr[4 + q];
      // H = T @ W2 + b2  (C-layout)
      f4v hc[4];
      #pragma unroll
      for (int nt = 0; nt < 4; nt++){
        f4v ci = { b24[nt], b24[nt], b24[nt], b24[nt] };
        hc[nt] = __builtin_amdgcn_mfma_f32_16x16x32_bf16(tf0, w2f[2*nt+0], ci, 0, 0, 0);
        hc[nt] = __builtin_amdgcn_mfma_f32_16x16x32_bf16(tf1, w2f[2*nt+1], hc[nt], 0, 0, 0);
      }
      // softmax over 16 neighbor-rows per column; then pre = sum attn*(v+p)
      float pre4[4];
      #pragma unroll
      for (int nt = 0; nt < 4; nt++){
        float mx = fmaxf(fmaxf(hc[nt][0], hc[nt][1]), fmaxf(hc[nt][2], hc[nt][3]));
        mx = fmaxf(mx, __shfl_xor(mx, 16, 64));
        mx = fmaxf(mx, __shfl_xor(mx, 32, 64));
        float s = 0.f;
        #pragma unroll
        for (int r = 0; r < 4; r++){ float e = __expf(hc[nt][r] - mx); hc[nt][r] = e; s += e; }
        s += __shfl_xor(s, 16, 64);
        s += __shfl_xor(s, 32, 64);
        float inv = __builtin_amdgcn_rcpf(s);
        float acc = 0.f;
        #pragma unroll
        for (int r = 0; r < 4; r++){
          float vv = bf2f(Vgw[(q*4+r)*136 + nt*16 + cl]);
          acc = fmaf(hc[nt][r], vv + pc[nt][r], acc);
        }
        acc += __shfl_xor(acc, 16, 64);
        acc += __shfl_xor(acc, 32, 64);
        pre4[nt] = acc * inv;
      }
      // lane l owns channel l: select tile (l>>4), store row pt
      float sa = (l & 16) ? pre4[1] : pre4[0];
      float sb = (l & 16) ? pre4[3] : pre4[2];
      PreBw[pt*68 + l] = (l & 32) ? sb : sa;
    }
  }
  // inline epilogue: out rows = PreB(16x64) @ Wo + bo
  s8v wof[8];
  {
    const s8v* Wop = (const s8v*)W.Wof;
    #pragma unroll
    for (int f = 0; f < 8; f++) wof[f] = Wop[f*64 + l];
  }
  s8v ef0, ef1;
  {
    const f4v* pr = (const f4v*)&PreBw[cl*68 + q*8];
    ef0 = pack8(pr[0], pr[1]);
    pr = (const f4v*)&PreBw[cl*68 + 32 + q*8];
    ef1 = pack8(pr[0], pr[1]);
  }
  #pragma unroll
  for (int nt = 0; nt < 4; nt++){
    float bn = P.bo[nt*16 + cl];
    f4v ci = { bn, bn, bn, bn };
    f4v oc = __builtin_amdgcn_mfma_f32_16x16x32_bf16(ef0, wof[2*nt+0], ci, 0, 0, 0);
    oc = __builtin_amdgcn_mfma_f32_16x16x32_bf16(ef1, wof[2*nt+1], oc, 0, 0, 0);
    #pragma unroll
    for (int r = 0; r < 4; r++){
      int rg = i0 + q*4 + r;
      if (rg < P.N) P.out[(size_t)rg*64 + nt*16 + cl] = oc[r];
    }
  }
}

extern "C" void kernel_launch(void* const* d_in, const int* in_sizes, int n_in,
                              void* d_out, int out_size, void* d_ws, size_t ws_size,
                              hipStream_t stream){
  InP P;
  P.points   = (const float*)d_in[0];
  P.features = (const float*)d_in[1];
  P.gidx     = (const int*)d_in[2];
  P.Wq  = (const float*)d_in[3];  P.bq  = (const float*)d_in[4];
  P.Wk  = (const float*)d_in[5];  P.bk  = (const float*)d_in[6];
  P.Wv  = (const float*)d_in[7];  P.bv  = (const float*)d_in[8];
  P.Wp  = (const float*)d_in[9];  P.b_p = (const float*)d_in[10];
  P.bnp_g = (const float*)d_in[11]; P.bnp_b = (const float*)d_in[12];
  P.bnp_m = (const float*)d_in[13]; P.bnp_v = (const float*)d_in[14];
  P.Wg1 = (const float*)d_in[15]; P.bg1 = (const float*)d_in[16];
  P.bng_g = (const float*)d_in[17]; P.bng_b = (const float*)d_in[18];
  P.bng_m = (const float*)d_in[19]; P.bng_v = (const float*)d_in[20];
  P.Wg2 = (const float*)d_in[21]; P.bg2 = (const float*)d_in[22];
  P.Wo  = (const float*)d_in[23]; P.bo  = (const float*)d_in[24];
  P.out = (float*)d_out;
  const int N = in_sizes[0] / 3;
  P.N = N;

  WS W;
  char* w = (char*)d_ws;
  W.qW1 = (unsigned short*)w; w += (size_t)N*64*2;
  W.kT  = (unsigned short*)w; w += (size_t)N*64*2;
  W.vT  = (unsigned short*)w; w += (size_t)N*64*2;
  W.WAf = (unsigned short*)w; w += 8*64*8*2;
  W.Wkf = (unsigned short*)w; w += 8*64*8*2;
  W.Wvf = (unsigned short*)w; w += 8*64*8*2;
  W.W1f = (unsigned short*)w; w += 8*64*8*2;
  W.W2f = (unsigned short*)w; w += 8*64*8*2;
  W.Wof = (unsigned short*)w; w += 8*64*8*2;
  W.Wpf = (unsigned short*)w; w += 4*64*8*2;
  W.bq1F = (float*)w; w += 256;
  W.bpF  = (float*)w; w += 256;

  const int TILES = (N + 15) / 16;
  const int grid = (TILES + TW - 1) / TW;
  hipLaunchKernelGGL(prep_kernel, dim3(1),    dim3(256), 0, stream, P, W);
  hipLaunchKernelGGL(qkv_kernel,  dim3(grid), dim3(256), 0, stream, P, W);
  hipLaunchKernelGGL(main_kernel, dim3(grid), dim3(256), 0, stream, P, W);
}